// Round 12
// baseline (201.789 us; speedup 1.0000x reference)
//
#include <hip/hip_runtime.h>
#include <hip/hip_bf16.h>
#include <math.h>

#define LQ 1024
#define DH 1024
#define NH 16
#define DKH 64

typedef __bf16 bf16x8 __attribute__((ext_vector_type(8)));
typedef float f32x4 __attribute__((ext_vector_type(4)));
typedef const unsigned int __attribute__((address_space(1)))* gas1_t;
typedef unsigned int __attribute__((address_space(3)))* las3_t;

__device__ __forceinline__ unsigned pack2bf(float a, float b) {
  union { __hip_bfloat16 h[2]; unsigned u; } t;
  t.h[0] = __float2bfloat16(a);
  t.h[1] = __float2bfloat16(b);
  return t.u;
}
__device__ __forceinline__ unsigned short bfbits(float x) {
  __hip_bfloat16 h = __float2bfloat16(x);
  return *(unsigned short*)&h;
}
__device__ __forceinline__ void bf4w(float* dst, uint2 r) {
  dst[0] = __uint_as_float(r.x << 16);
  dst[1] = __uint_as_float(r.x & 0xffff0000u);
  dst[2] = __uint_as_float(r.y << 16);
  dst[3] = __uint_as_float(r.y & 0xffff0000u);
}

// ---------------- fused prep: physics + x->bf16 + W_qkv^T + W_o^T ----------------
__global__ __launch_bounds__(256) void prep_kernel(
    const float* __restrict__ x, const float* __restrict__ W_qkv, const float* __restrict__ W_o,
    const float* __restrict__ W_LTM, const float* __restrict__ V_gs, const float* __restrict__ V_T0,
    const float* __restrict__ beta_tau, const float* __restrict__ beta_gm, const float* __restrict__ C_ch,
    const float* __restrict__ gamma_, const float* __restrict__ alpha_ppd, const float* __restrict__ IC_thr,
    const float* __restrict__ gate,
    __hip_bfloat16* __restrict__ xb, __hip_bfloat16* __restrict__ wqt, __hip_bfloat16* __restrict__ wot,
    float* __restrict__ ret, float* __restrict__ ret64, float* __restrict__ co, float* __restrict__ g_out) {
  __shared__ float ts[32][33];
  const int bx = blockIdx.x, tid = threadIdx.x;
  if (bx < 256) {
    int idx = bx * 256 + tid;
    int h = idx >> 12;
    float w = W_LTM[idx];
    float veff = V_gs[h] - V_T0[h] + w;
    float sp = fmaxf(veff, 0.f) + log1pf(expf(-fabsf(veff)));
    float gch = beta_tau[h] * sp;
    float e1 = gch / C_ch[h];
    float sig = 1.f / (1.f + expf(-veff));
    float G = beta_gm[h] * sp * sig;
    float sm = tanhf(alpha_ppd[0] * (gch - IC_thr[0]));
    ret[idx] = expf(-e1);
    ret64[idx] = expf(-64.f * e1);
    co[idx] = gamma_[h] * sm * G;
    if (idx < NH) g_out[idx] = 1.f / (1.f + expf(-gate[idx]));
  } else if (bx < 2304) {
    size_t i = (size_t)((bx - 256) * 256 + tid) * 4;
    float4 v = *(const float4*)(x + i);
    __hip_bfloat16 t[4] = {__float2bfloat16(v.x), __float2bfloat16(v.y),
                           __float2bfloat16(v.z), __float2bfloat16(v.w)};
    *(uint2*)(xb + i) = *(uint2*)t;
  } else {
    const float* W;
    __hip_bfloat16* Wt;
    int n0, k0, N;
    if (bx < 5376) {
      int idx = bx - 2304;
      W = W_qkv; Wt = wqt; N = 3072;
      n0 = (idx % 96) * 32; k0 = (idx / 96) * 32;
    } else {
      int idx = bx - 5376;
      W = W_o; Wt = wot; N = 1024;
      n0 = (idx & 31) * 32; k0 = (idx >> 5) * 32;
    }
    int r = tid >> 5, c = tid & 31;
#pragma unroll
    for (int i = 0; i < 4; i++) ts[r + 8 * i][c] = W[(size_t)(k0 + r + 8 * i) * N + n0 + c];
    __syncthreads();
#pragma unroll
    for (int i = 0; i < 4; i++)
      Wt[(size_t)(n0 + r + 8 * i) * 1024 + k0 + c] = __float2bfloat16(ts[c][r + 8 * i]);
  }
}

// ---------------- qkv GEMM 64x128 tiles (768 blocks, 3/CU) + fused LN(k) + v^T ----------------
__global__ __launch_bounds__(256) void gemm_qkv_kernel(
    const __hip_bfloat16* __restrict__ A, const __hip_bfloat16* __restrict__ Bt,
    __hip_bfloat16* __restrict__ C, __hip_bfloat16* __restrict__ knb,
    __hip_bfloat16* __restrict__ vt, int M, int N, int K) {
  __shared__ union {
    struct { unsigned short As[64 * 32]; unsigned short Bs[128 * 32]; } ab;
    unsigned short Vt[4][64][36];
  } sm;
  const int tid = threadIdx.x;
  const int w = tid >> 6, lane = tid & 63;
  const int quad = lane >> 4, l16 = lane & 15;
  const int wm = w & 1, wn = w >> 1;
  const int row0 = blockIdx.y * 64, col0 = blockIdx.x * 128;
  const int sr = lane >> 2;
  const int sk = (lane & 3) * 8;
  f32x4 acc[2][4];
#pragma unroll
  for (int i = 0; i < 2; i++)
#pragma unroll
    for (int j = 0; j < 4; j++) acc[i][j] = (f32x4){0.f, 0.f, 0.f, 0.f};

  for (int k0 = 0; k0 < K; k0 += 32) {
    __syncthreads();
    {
      const __hip_bfloat16* gA = A + (size_t)(row0 + w * 16 + sr) * K + k0 + sk;
      __builtin_amdgcn_global_load_lds((gas1_t)gA, (las3_t)((char*)sm.ab.As + w * 1024), 16, 0, 0);
#pragma unroll
      for (int c = 0; c < 2; c++) {
        int s = c * 4 + w;
        const __hip_bfloat16* gB = Bt + (size_t)(col0 + s * 16 + sr) * K + k0 + sk;
        __builtin_amdgcn_global_load_lds((gas1_t)gB, (las3_t)((char*)sm.ab.Bs + s * 1024), 16, 0, 0);
      }
    }
    __syncthreads();
    bf16x8 af[2], bfr[4];
#pragma unroll
    for (int i = 0; i < 2; i++)
      af[i] = *(const bf16x8*)((const char*)sm.ab.As + (((wm * 32 + i * 16 + l16) * 32 + quad * 8) << 1));
#pragma unroll
    for (int j = 0; j < 4; j++)
      bfr[j] = *(const bf16x8*)((const char*)sm.ab.Bs + (((wn * 64 + j * 16 + l16) * 32 + quad * 8) << 1));
#pragma unroll
    for (int i = 0; i < 2; i++)
#pragma unroll
      for (int j = 0; j < 4; j++)
        acc[i][j] = __builtin_amdgcn_mfma_f32_16x16x32_bf16(af[i], bfr[j], acc[i][j], 0, 0, 0);
  }
#pragma unroll
  for (int i = 0; i < 2; i++) {
    int rowb = row0 + wm * 32 + i * 16 + quad * 4;
#pragma unroll
    for (int j = 0; j < 4; j++) {
      int col = col0 + wn * 64 + j * 16 + l16;
#pragma unroll
      for (int r = 0; r < 4; r++)
        C[(size_t)(rowb + r) * N + col] = __float2bfloat16(acc[i][j][r]);
    }
  }
  const int sec = col0 >> 10;
  const int hh = ((col0 & 1023) >> 6) + wn;
  if (sec == 1) {
#pragma unroll
    for (int i = 0; i < 2; i++) {
      f32x4 s1 = {0.f, 0.f, 0.f, 0.f}, s2 = {0.f, 0.f, 0.f, 0.f};
#pragma unroll
      for (int j = 0; j < 4; j++)
#pragma unroll
        for (int r = 0; r < 4; r++) {
          s1[r] += acc[i][j][r];
          s2[r] += acc[i][j][r] * acc[i][j][r];
        }
#pragma unroll
      for (int m = 1; m <= 8; m <<= 1)
#pragma unroll
        for (int r = 0; r < 4; r++) {
          s1[r] += __shfl_xor(s1[r], m);
          s2[r] += __shfl_xor(s2[r], m);
        }
#pragma unroll
      for (int r = 0; r < 4; r++) {
        float mu = s1[r] * (1.f / 64.f);
        float var = s2[r] * (1.f / 64.f) - mu * mu;
        float inv = rsqrtf(var + 1e-5f);
        int row = row0 + wm * 32 + i * 16 + quad * 4 + r;
#pragma unroll
        for (int j = 0; j < 4; j++)
          knb[((size_t)row * NH + hh) * DKH + j * 16 + l16] = __float2bfloat16((acc[i][j][r] - mu) * inv);
      }
    }
  } else if (sec == 2) {
    __syncthreads();
#pragma unroll
    for (int i = 0; i < 2; i++)
#pragma unroll
      for (int j = 0; j < 4; j++)
#pragma unroll
        for (int r = 0; r < 4; r++)
          sm.Vt[w][j * 16 + l16][i * 16 + quad * 4 + r] = bfbits(acc[i][j][r]);
    const int b = row0 >> 10;
    const int t0 = (row0 & 1023) + wm * 32;
    const int bh = b * NH + hh;
    const int cc = lane & 3, ddl = lane >> 2;
#pragma unroll
    for (int pass = 0; pass < 4; pass++) {
      int d = pass * 16 + ddl;
      uint2 a0 = *(const uint2*)&sm.Vt[w][d][cc * 8];
      uint2 a1 = *(const uint2*)&sm.Vt[w][d][cc * 8 + 4];
      uint4 val = {a0.x, a0.y, a1.x, a1.y};
      *(uint4*)(vt + ((size_t)bh * DKH + d) * LQ + t0 + cc * 8) = val;
    }
  }
}

// ---------------- out GEMM: 64x64 tiles, BK=64, fragment-major LDS ----------------
__global__ __launch_bounds__(256) void gemm_out_kernel(
    const __hip_bfloat16* __restrict__ A, const __hip_bfloat16* __restrict__ Bt,
    float* __restrict__ C, int M, int N, int K) {
  __shared__ unsigned short As[8 * 512];
  __shared__ unsigned short Bs[8 * 512];
  const int tid = threadIdx.x;
  const int w = tid >> 6, lane = tid & 63;
  const int quad = lane >> 4, l16 = lane & 15;
  const int wm = w & 1, wn = w >> 1;
  const int row0 = blockIdx.y * 64, col0 = blockIdx.x * 64;
  const int fr = lane & 15;
  const int fk = (lane >> 4) * 8;
  f32x4 acc[2][2];
#pragma unroll
  for (int i = 0; i < 2; i++)
#pragma unroll
    for (int j = 0; j < 2; j++) acc[i][j] = (f32x4){0.f, 0.f, 0.f, 0.f};

  for (int k0 = 0; k0 < K; k0 += 64) {
    __syncthreads();
#pragma unroll
    for (int kk = 0; kk < 2; kk++) {
      const int f = kk * 4 + w;
      const __hip_bfloat16* gA = A + (size_t)(row0 + w * 16 + fr) * K + k0 + kk * 32 + fk;
      __builtin_amdgcn_global_load_lds((gas1_t)gA, (las3_t)((char*)As + f * 1024), 16, 0, 0);
      const __hip_bfloat16* gB = Bt + (size_t)(col0 + w * 16 + fr) * K + k0 + kk * 32 + fk;
      __builtin_amdgcn_global_load_lds((gas1_t)gB, (las3_t)((char*)Bs + f * 1024), 16, 0, 0);
    }
    __syncthreads();
#pragma unroll
    for (int kk = 0; kk < 2; kk++) {
      bf16x8 af[2], bfr[2];
#pragma unroll
      for (int i = 0; i < 2; i++)
        af[i] = *(const bf16x8*)((const char*)As + (((kk * 4 + wm * 2 + i) * 64 + lane) << 4));
#pragma unroll
      for (int j = 0; j < 2; j++)
        bfr[j] = *(const bf16x8*)((const char*)Bs + (((kk * 4 + wn * 2 + j) * 64 + lane) << 4));
#pragma unroll
      for (int i = 0; i < 2; i++)
#pragma unroll
        for (int j = 0; j < 2; j++)
          acc[i][j] = __builtin_amdgcn_mfma_f32_16x16x32_bf16(af[i], bfr[j], acc[i][j], 0, 0, 0);
    }
  }
#pragma unroll
  for (int i = 0; i < 2; i++) {
    int rowb = row0 + wm * 32 + i * 16 + quad * 4;
#pragma unroll
    for (int j = 0; j < 2; j++) {
      int col = col0 + wn * 32 + j * 16 + l16;
#pragma unroll
      for (int r = 0; r < 4; r++)
        C[(size_t)(rowb + r) * N + col] = acc[i][j][r];
    }
  }
}

// ---------------- FUSED attn (blocks 0..511) + scan state pass (blocks 512..1471) ----------------
__global__ __launch_bounds__(256) void attn_state_kernel(
    const __hip_bfloat16* __restrict__ qkvb, const __hip_bfloat16* __restrict__ vt,
    __hip_bfloat16* __restrict__ sob, const __hip_bfloat16* __restrict__ knb,
    const float* __restrict__ ret_g, const float* __restrict__ co_g, float* __restrict__ S) {
  __shared__ __attribute__((aligned(16))) union {
    struct { __hip_bfloat16 Ks[8 * 64 * 8]; __hip_bfloat16 Vs[8 * 64 * 8]; } at;  // 16 KB
    struct { float kb[2][8][64]; float vb[2][8][64]; } st;                        // 8 KB
  } sm;
  const int bx = blockIdx.x;
  const int tid = threadIdx.x;
  if (bx < 512) {
    // ===== attention =====
    const int it = 15 - (bx & 15);
    const int h = (bx >> 4) & 15, b = bx >> 8;
    const int bh = b * NH + h;
    const int w = tid >> 6, lane = tid & 63;
    const int l16 = lane & 15, quad = lane >> 4;
    const int i0 = it * 64;
    const int q_abs = i0 + w * 16 + l16;
    bf16x8 aq[2];
    aq[0] = *(const bf16x8*)(qkvb + (size_t)(b * LQ + q_abs) * 3 * DH + h * DKH + quad * 8);
    aq[1] = *(const bf16x8*)(qkvb + (size_t)(b * LQ + q_abs) * 3 * DH + h * DKH + 32 + quad * 8);
    f32x4 o[4];
#pragma unroll
    for (int dt = 0; dt < 4; dt++) o[dt] = (f32x4){0.f, 0.f, 0.f, 0.f};
    float mrun = -3e38f, lrun = 0.f;

    for (int jt = 0; jt <= it; jt++) {
      const int j0 = jt * 64;
      __syncthreads();
#pragma unroll
      for (int ff = 0; ff < 2; ff++) {
        const int f = w * 2 + ff;
        const int nt = f >> 1, kk = f & 1;
        const __hip_bfloat16* gk = qkvb + (size_t)(b * LQ + j0 + nt * 16 + l16) * 3 * DH + DH +
                                   h * DKH + kk * 32 + quad * 8;
        __builtin_amdgcn_global_load_lds((gas1_t)gk, (las3_t)(sm.at.Ks + f * 512), 16, 0, 0);
        const __hip_bfloat16* gv = vt + ((size_t)bh * DKH + nt * 16 + l16) * LQ + j0 + kk * 32 + quad * 8;
        __builtin_amdgcn_global_load_lds((gas1_t)gv, (las3_t)(sm.at.Vs + f * 512), 16, 0, 0);
      }
      __syncthreads();
      f32x4 s[4];
#pragma unroll
      for (int nt = 0; nt < 4; nt++) s[nt] = (f32x4){0.f, 0.f, 0.f, 0.f};
#pragma unroll
      for (int kk = 0; kk < 2; kk++)
#pragma unroll
        for (int nt = 0; nt < 4; nt++) {
          bf16x8 bk = *(const bf16x8*)(sm.at.Ks + ((nt * 2 + kk) * 64 + lane) * 8);
          s[nt] = __builtin_amdgcn_mfma_f32_16x16x32_bf16(bk, aq[kk], s[nt], 0, 0, 0);
        }
#pragma unroll
      for (int nt = 0; nt < 4; nt++)
#pragma unroll
        for (int r = 0; r < 4; r++) {
          float sv = s[nt][r] * 0.125f;
          if (jt == it && (j0 + nt * 16 + quad * 4 + r > q_abs)) sv = -1e30f;
          s[nt][r] = sv;
        }
      float mx = -3e38f;
#pragma unroll
      for (int nt = 0; nt < 4; nt++)
#pragma unroll
        for (int r = 0; r < 4; r++) mx = fmaxf(mx, s[nt][r]);
      mx = fmaxf(mx, __shfl_xor(mx, 16));
      mx = fmaxf(mx, __shfl_xor(mx, 32));
      float mn = fmaxf(mrun, mx);
      float al = __expf(mrun - mn);
      mrun = mn;
      float p[4][4];
      float rs = 0.f;
#pragma unroll
      for (int nt = 0; nt < 4; nt++)
#pragma unroll
        for (int r = 0; r < 4; r++) {
          float pv = __expf(s[nt][r] - mn);
          p[nt][r] = pv;
          rs += pv;
        }
      rs += __shfl_xor(rs, 16);
      rs += __shfl_xor(rs, 32);
      lrun = lrun * al + rs;
      unsigned pk[4][2];
#pragma unroll
      for (int nt = 0; nt < 4; nt++) {
        pk[nt][0] = pack2bf(p[nt][0], p[nt][1]);
        pk[nt][1] = pack2bf(p[nt][2], p[nt][3]);
      }
      const int srcA = l16 | ((quad & 1) << 5);
      const bool hi_sel = (quad >> 1) != 0;
      bf16x8 ap[2];
#pragma unroll
      for (int kk = 0; kk < 2; kk++) {
        union { unsigned u[4]; bf16x8 v; } cv;
#pragma unroll
        for (int gi = 0; gi < 2; gi++) {
          int src = srcA + (gi << 4);
          unsigned lo0 = (unsigned)__shfl((int)pk[kk * 2][0], src);
          unsigned lo1 = (unsigned)__shfl((int)pk[kk * 2][1], src);
          unsigned hi0 = (unsigned)__shfl((int)pk[kk * 2 + 1][0], src);
          unsigned hi1 = (unsigned)__shfl((int)pk[kk * 2 + 1][1], src);
          cv.u[gi * 2] = hi_sel ? hi0 : lo0;
          cv.u[gi * 2 + 1] = hi_sel ? hi1 : lo1;
        }
        ap[kk] = cv.v;
      }
#pragma unroll
      for (int dt = 0; dt < 4; dt++)
#pragma unroll
        for (int r = 0; r < 4; r++) o[dt][r] *= al;
#pragma unroll
      for (int kk = 0; kk < 2; kk++)
#pragma unroll
        for (int dt = 0; dt < 4; dt++) {
          bf16x8 bv = *(const bf16x8*)(sm.at.Vs + ((dt * 2 + kk) * 64 + lane) * 8);
          o[dt] = __builtin_amdgcn_mfma_f32_16x16x32_bf16(bv, ap[kk], o[dt], 0, 0, 0);
        }
    }
    float inv = 1.f / lrun;
    __hip_bfloat16* ob = sob + ((size_t)(b * LQ + q_abs) * NH + h) * DKH + quad * 4;
#pragma unroll
    for (int dt = 0; dt < 4; dt++) {
      uint2 val = {pack2bf(o[dt][0] * inv, o[dt][1] * inv),
                   pack2bf(o[dt][2] * inv, o[dt][3] * inv)};
      *(uint2*)(ob + dt * 16) = val;
    }
  } else {
    // ===== scan state pass (chunks 0..14) =====
    const int sx = bx - 512;
    const int c = sx >> 6;
    const int xr = sx & 63;
    const int bh = xr >> 1;
    const int half = xr & 1;
    const int bb = bh >> 4, h = bh & 15;
    const int dl = tid >> 3, j = tid & 7;
    const int d = half * 32 + dl;
    float F[8], R[8], Cc[8];
    const int base = h * 4096 + d * 64 + j * 8;
#pragma unroll
    for (int i = 0; i < 8; i++) {
      F[i] = 0.f;
      R[i] = ret_g[base + i];
      Cc[i] = co_g[base + i];
    }
    const int t00 = c * 64;
    const int sten = tid >> 7;
    const int sli = tid & 127;
    const int ss = sli >> 4;
    const int se = (sli & 15) * 4;
    {
      int t = t00 + ss;
      uint2 raw = (sten == 0)
          ? *(const uint2*)(knb + ((size_t)(bb * LQ + t) * NH + h) * DKH + se)
          : *(const uint2*)(qkvb + ((size_t)(bb * LQ + t) * 3 + 2) * DH + h * DKH + se);
      bf4w(sten == 0 ? &sm.st.kb[0][ss][se] : &sm.st.vb[0][ss][se], raw);
    }
    __syncthreads();
    for (int sc = 0; sc < 8; sc++) {
      const int p = sc & 1;
      uint2 raw;
      if (sc < 7) {
        int t = t00 + (sc + 1) * 8 + ss;
        raw = (sten == 0)
            ? *(const uint2*)(knb + ((size_t)(bb * LQ + t) * NH + h) * DKH + se)
            : *(const uint2*)(qkvb + ((size_t)(bb * LQ + t) * 3 + 2) * DH + h * DKH + se);
      }
#pragma unroll
      for (int s = 0; s < 8; s++) {
        float vd = sm.st.vb[p][s][d];
        float4 k0 = *(const float4*)&sm.st.kb[p][s][j * 8];
        float4 k1 = *(const float4*)&sm.st.kb[p][s][j * 8 + 4];
        float ke[8] = {k0.x, k0.y, k0.z, k0.w, k1.x, k1.y, k1.z, k1.w};
#pragma unroll
        for (int i = 0; i < 8; i++) F[i] = fmaf(Cc[i] * vd, ke[i], R[i] * F[i]);
      }
      if (sc < 7) bf4w(sten == 0 ? &sm.st.kb[p ^ 1][ss][se] : &sm.st.vb[p ^ 1][ss][se], raw);
      __syncthreads();
    }
    const size_t sb = ((size_t)c * 2048 + ((size_t)bb * 16 + h) * 64 + d) * 64 + j * 8;
#pragma unroll
    for (int i = 0; i < 8; i++) S[sb + i] = F[i];
  }
}

// ---------------- scan_out with fused combine prologue + gate-mix ----------------
__global__ __launch_bounds__(256) void scan_out_kernel(
    const __hip_bfloat16* __restrict__ qkvb, const __hip_bfloat16* __restrict__ knb,
    const float* __restrict__ W_LTM, const float* __restrict__ ret_g, const float* __restrict__ co_g,
    const float* __restrict__ S, const float* __restrict__ ret64,
    const __hip_bfloat16* __restrict__ sob, const float* __restrict__ g,
    __hip_bfloat16* __restrict__ mixb) {
  const int bh = blockIdx.x >> 1;
  const int half = blockIdx.x & 1;
  const int c = blockIdx.y;                 // 0..15
  const int bb = bh >> 4, h = bh & 15;
  const int tid = threadIdx.x;
  const int dl = tid >> 3, j = tid & 7;
  const int d = half * 32 + dl;
  const float gh = g[h];
  float F[8], R[8], Cc[8], W[8];
  const int base = h * 4096 + d * 64 + j * 8;
#pragma unroll
  for (int i = 0; i < 8; i++) {
    F[i] = 0.f;
    R[i] = ret_g[base + i];
    Cc[i] = co_g[base + i];
    W[i] = W_LTM[base + i];
  }
  // combine prologue: F = sum_{cc<c} r64^{c-1-cc} * S[cc]  (identical fmaf chain to old combine)
  if (c > 0) {
    float r64v[8];
#pragma unroll
    for (int i = 0; i < 8; i++) r64v[i] = ret64[base + i];
    const size_t srow = (((size_t)bb * 16 + h) * 64 + d) * 64 + j * 8;
    for (int cc = 0; cc < c; cc++) {
      const float* sp = S + (size_t)cc * 131072 + srow;
      float4 s0 = *(const float4*)sp;
      float4 s1 = *(const float4*)(sp + 4);
      float sv[8] = {s0.x, s0.y, s0.z, s0.w, s1.x, s1.y, s1.z, s1.w};
#pragma unroll
      for (int i = 0; i < 8; i++) F[i] = fmaf(r64v[i], F[i], sv[i]);
    }
  }
  __shared__ float qb[2][8][64], kb[2][8][64], vb[2][8][64];
  const int t00 = c * 64;
  const int sten = tid >> 7;
  const int sli = tid & 127;
  const int ss = sli >> 4;
  const int se = (sli & 15) * 4;
  const int vs = tid >> 5;
  const int ve = (tid & 31) * 2;
  {
    int t = t00 + ss, tv = t00 + vs;
    uint2 rqk = (sten == 0)
        ? *(const uint2*)(qkvb + (size_t)(bb * LQ + t) * 3 * DH + h * DKH + se)
        : *(const uint2*)(knb + ((size_t)(bb * LQ + t) * NH + h) * DKH + se);
    unsigned rv = *(const unsigned*)(qkvb + ((size_t)(bb * LQ + tv) * 3 + 2) * DH + h * DKH + ve);
    bf4w(sten == 0 ? &qb[0][ss][se] : &kb[0][ss][se], rqk);
    vb[0][vs][ve] = __uint_as_float(rv << 16);
    vb[0][vs][ve + 1] = __uint_as_float(rv & 0xffff0000u);
  }
  __syncthreads();
  for (int sc = 0; sc < 8; sc++) {
    const int p = sc & 1;
    uint2 rqk;
    unsigned rv;
    if (sc < 7) {
      int t = t00 + (sc + 1) * 8 + ss, tv = t00 + (sc + 1) * 8 + vs;
      rqk = (sten == 0)
          ? *(const uint2*)(qkvb + (size_t)(bb * LQ + t) * 3 * DH + h * DKH + se)
          : *(const uint2*)(knb + ((size_t)(bb * LQ + t) * NH + h) * DKH + se);
      rv = *(const unsigned*)(qkvb + ((size_t)(bb * LQ + tv) * 3 + 2) * DH + h * DKH + ve);
    }
    float ykeep = 0.f;
#pragma unroll
    for (int s = 0; s < 8; s++) {
      float vd = vb[p][s][d];
      float4 k0 = *(const float4*)&kb[p][s][j * 8];
      float4 k1 = *(const float4*)&kb[p][s][j * 8 + 4];
      float4 q0 = *(const float4*)&qb[p][s][j * 8];
      float4 q1 = *(const float4*)&qb[p][s][j * 8 + 4];
      float ke[8] = {k0.x, k0.y, k0.z, k0.w, k1.x, k1.y, k1.z, k1.w};
      float qe[8] = {q0.x, q0.y, q0.z, q0.w, q1.x, q1.y, q1.z, q1.w};
      float yp = 0.f;
#pragma unroll
      for (int i = 0; i < 8; i++) {
        F[i] = fmaf(Cc[i] * vd, ke[i], R[i] * F[i]);
        yp = fmaf(W[i] + F[i], qe[i], yp);
      }
      yp += __shfl_xor(yp, 1);
      yp += __shfl_xor(yp, 2);
      yp += __shfl_xor(yp, 4);
      if (j == s) ykeep = yp;
    }
    {
      const size_t oi = ((size_t)(bb * LQ + t00 + sc * 8 + j) * NH + h) * DKH + d;
      float sv = __bfloat162float(sob[oi]);
      mixb[oi] = __float2bfloat16(gh * sv + (1.f - gh) * ykeep);
    }
    if (sc < 7) {
      bf4w(sten == 0 ? &qb[p ^ 1][ss][se] : &kb[p ^ 1][ss][se], rqk);
      vb[p ^ 1][vs][ve] = __uint_as_float(rv << 16);
      vb[p ^ 1][vs][ve + 1] = __uint_as_float(rv & 0xffff0000u);
    }
    __syncthreads();
  }
}

extern "C" void kernel_launch(void* const* d_in, const int* in_sizes, int n_in,
                              void* d_out, int out_size, void* d_ws, size_t ws_size,
                              hipStream_t stream) {
  (void)in_sizes; (void)n_in; (void)out_size; (void)ws_size;
  const float* x        = (const float*)d_in[0];
  const float* W_qkv    = (const float*)d_in[1];
  const float* W_o      = (const float*)d_in[2];
  const float* W_LTM    = (const float*)d_in[3];
  const float* V_gs     = (const float*)d_in[4];
  const float* V_T0     = (const float*)d_in[5];
  const float* beta_tau = (const float*)d_in[6];
  const float* beta_gm  = (const float*)d_in[7];
  const float* C_ch     = (const float*)d_in[8];
  const float* gamma_   = (const float*)d_in[9];
  const float* alpha_p  = (const float*)d_in[10];
  const float* IC_thr   = (const float*)d_in[11];
  const float* gate     = (const float*)d_in[12];

  float* ws  = (float*)d_ws;
  __hip_bfloat16* qkvb = (__hip_bfloat16*)ws;             // 6291456 bf16
  __hip_bfloat16* knb  = (__hip_bfloat16*)(ws + 3145728); // 2097152 bf16
  __hip_bfloat16* sob  = (__hip_bfloat16*)(ws + 4194304); // 2097152 bf16
  __hip_bfloat16* mixb = (__hip_bfloat16*)(ws + 5242880); // 2097152 bf16
  __hip_bfloat16* vtb  = (__hip_bfloat16*)(ws + 6291456); // 2097152 bf16
  __hip_bfloat16* xb   = (__hip_bfloat16*)(ws + 7340032); // 2097152 bf16
  __hip_bfloat16* wqt  = (__hip_bfloat16*)(ws + 8388608); // 3145728 bf16
  __hip_bfloat16* wot  = (__hip_bfloat16*)(ws + 9961472); // 1048576 bf16
  float* ret   = ws + 10485760;    // 65536
  float* ret64 = ret + 65536;      // 65536
  float* co    = ret64 + 65536;    // 65536
  float* g     = co + 65536;       // 64
  float* Sbuf  = g + 64;           // 15*131072
  float* out = (float*)d_out;

  prep_kernel<<<6400, 256, 0, stream>>>(x, W_qkv, W_o, W_LTM, V_gs, V_T0, beta_tau, beta_gm,
                                        C_ch, gamma_, alpha_p, IC_thr, gate,
                                        xb, wqt, wot, ret, ret64, co, g);
  gemm_qkv_kernel<<<dim3(24, 32), 256, 0, stream>>>(xb, wqt, qkvb, knb, vtb, 2048, 3072, 1024);
  attn_state_kernel<<<1472, 256, 0, stream>>>(qkvb, vtb, sob, knb, ret, co, Sbuf);
  scan_out_kernel<<<dim3(64, 16), 256, 0, stream>>>(qkvb, knb, W_LTM, ret, co, Sbuf, ret64, sob, g, mixb);
  gemm_out_kernel<<<dim3(16, 32), 256, 0, stream>>>(mixb, wot, out, 2048, 1024, 1024);
}

// Round 13
// 194.886 us; speedup vs baseline: 1.0354x; 1.0354x over previous
//
#include <hip/hip_runtime.h>
#include <hip/hip_bf16.h>
#include <math.h>

#define LQ 1024
#define DH 1024
#define NH 16
#define DKH 64

typedef __bf16 bf16x8 __attribute__((ext_vector_type(8)));
typedef float f32x4 __attribute__((ext_vector_type(4)));
typedef const unsigned int __attribute__((address_space(1)))* gas1_t;
typedef unsigned int __attribute__((address_space(3)))* las3_t;

__device__ __forceinline__ unsigned pack2bf(float a, float b) {
  union { __hip_bfloat16 h[2]; unsigned u; } t;
  t.h[0] = __float2bfloat16(a);
  t.h[1] = __float2bfloat16(b);
  return t.u;
}
__device__ __forceinline__ unsigned short bfbits(float x) {
  __hip_bfloat16 h = __float2bfloat16(x);
  return *(unsigned short*)&h;
}
__device__ __forceinline__ void bf4w(float* dst, uint2 r) {
  dst[0] = __uint_as_float(r.x << 16);
  dst[1] = __uint_as_float(r.x & 0xffff0000u);
  dst[2] = __uint_as_float(r.y << 16);
  dst[3] = __uint_as_float(r.y & 0xffff0000u);
}

// ---------------- fused prep: physics + x->bf16 + W_qkv^T + W_o^T ----------------
__global__ __launch_bounds__(256) void prep_kernel(
    const float* __restrict__ x, const float* __restrict__ W_qkv, const float* __restrict__ W_o,
    const float* __restrict__ W_LTM, const float* __restrict__ V_gs, const float* __restrict__ V_T0,
    const float* __restrict__ beta_tau, const float* __restrict__ beta_gm, const float* __restrict__ C_ch,
    const float* __restrict__ gamma_, const float* __restrict__ alpha_ppd, const float* __restrict__ IC_thr,
    const float* __restrict__ gate,
    __hip_bfloat16* __restrict__ xb, __hip_bfloat16* __restrict__ wqt, __hip_bfloat16* __restrict__ wot,
    float* __restrict__ ret, float* __restrict__ ret64, float* __restrict__ co, float* __restrict__ g_out) {
  __shared__ float ts[32][33];
  const int bx = blockIdx.x, tid = threadIdx.x;
  if (bx < 256) {
    int idx = bx * 256 + tid;
    int h = idx >> 12;
    float w = W_LTM[idx];
    float veff = V_gs[h] - V_T0[h] + w;
    float sp = fmaxf(veff, 0.f) + log1pf(expf(-fabsf(veff)));
    float gch = beta_tau[h] * sp;
    float e1 = gch / C_ch[h];
    float sig = 1.f / (1.f + expf(-veff));
    float G = beta_gm[h] * sp * sig;
    float sm = tanhf(alpha_ppd[0] * (gch - IC_thr[0]));
    ret[idx] = expf(-e1);
    ret64[idx] = expf(-64.f * e1);
    co[idx] = gamma_[h] * sm * G;
    if (idx < NH) g_out[idx] = 1.f / (1.f + expf(-gate[idx]));
  } else if (bx < 2304) {
    size_t i = (size_t)((bx - 256) * 256 + tid) * 4;
    float4 v = *(const float4*)(x + i);
    __hip_bfloat16 t[4] = {__float2bfloat16(v.x), __float2bfloat16(v.y),
                           __float2bfloat16(v.z), __float2bfloat16(v.w)};
    *(uint2*)(xb + i) = *(uint2*)t;
  } else {
    const float* W;
    __hip_bfloat16* Wt;
    int n0, k0, N;
    if (bx < 5376) {
      int idx = bx - 2304;
      W = W_qkv; Wt = wqt; N = 3072;
      n0 = (idx % 96) * 32; k0 = (idx / 96) * 32;
    } else {
      int idx = bx - 5376;
      W = W_o; Wt = wot; N = 1024;
      n0 = (idx & 31) * 32; k0 = (idx >> 5) * 32;
    }
    int r = tid >> 5, c = tid & 31;
#pragma unroll
    for (int i = 0; i < 4; i++) ts[r + 8 * i][c] = W[(size_t)(k0 + r + 8 * i) * N + n0 + c];
    __syncthreads();
#pragma unroll
    for (int i = 0; i < 4; i++)
      Wt[(size_t)(n0 + r + 8 * i) * 1024 + k0 + c] = __float2bfloat16(ts[c][r + 8 * i]);
  }
}

// ---------------- qkv GEMM 64x128 tiles (768 blocks, 3/CU) + fused LN(k) + v^T ----------------
__global__ __launch_bounds__(256) void gemm_qkv_kernel(
    const __hip_bfloat16* __restrict__ A, const __hip_bfloat16* __restrict__ Bt,
    __hip_bfloat16* __restrict__ C, __hip_bfloat16* __restrict__ knb,
    __hip_bfloat16* __restrict__ vt, int M, int N, int K) {
  __shared__ union {
    struct { unsigned short As[64 * 32]; unsigned short Bs[128 * 32]; } ab;
    unsigned short Vt[4][64][36];
  } sm;
  const int tid = threadIdx.x;
  const int w = tid >> 6, lane = tid & 63;
  const int quad = lane >> 4, l16 = lane & 15;
  const int wm = w & 1, wn = w >> 1;
  const int row0 = blockIdx.y * 64, col0 = blockIdx.x * 128;
  const int sr = lane >> 2;
  const int sk = (lane & 3) * 8;
  f32x4 acc[2][4];
#pragma unroll
  for (int i = 0; i < 2; i++)
#pragma unroll
    for (int j = 0; j < 4; j++) acc[i][j] = (f32x4){0.f, 0.f, 0.f, 0.f};

  for (int k0 = 0; k0 < K; k0 += 32) {
    __syncthreads();
    {
      const __hip_bfloat16* gA = A + (size_t)(row0 + w * 16 + sr) * K + k0 + sk;
      __builtin_amdgcn_global_load_lds((gas1_t)gA, (las3_t)((char*)sm.ab.As + w * 1024), 16, 0, 0);
#pragma unroll
      for (int c = 0; c < 2; c++) {
        int s = c * 4 + w;
        const __hip_bfloat16* gB = Bt + (size_t)(col0 + s * 16 + sr) * K + k0 + sk;
        __builtin_amdgcn_global_load_lds((gas1_t)gB, (las3_t)((char*)sm.ab.Bs + s * 1024), 16, 0, 0);
      }
    }
    __syncthreads();
    bf16x8 af[2], bfr[4];
#pragma unroll
    for (int i = 0; i < 2; i++)
      af[i] = *(const bf16x8*)((const char*)sm.ab.As + (((wm * 32 + i * 16 + l16) * 32 + quad * 8) << 1));
#pragma unroll
    for (int j = 0; j < 4; j++)
      bfr[j] = *(const bf16x8*)((const char*)sm.ab.Bs + (((wn * 64 + j * 16 + l16) * 32 + quad * 8) << 1));
#pragma unroll
    for (int i = 0; i < 2; i++)
#pragma unroll
      for (int j = 0; j < 4; j++)
        acc[i][j] = __builtin_amdgcn_mfma_f32_16x16x32_bf16(af[i], bfr[j], acc[i][j], 0, 0, 0);
  }
#pragma unroll
  for (int i = 0; i < 2; i++) {
    int rowb = row0 + wm * 32 + i * 16 + quad * 4;
#pragma unroll
    for (int j = 0; j < 4; j++) {
      int col = col0 + wn * 64 + j * 16 + l16;
#pragma unroll
      for (int r = 0; r < 4; r++)
        C[(size_t)(rowb + r) * N + col] = __float2bfloat16(acc[i][j][r]);
    }
  }
  const int sec = col0 >> 10;
  const int hh = ((col0 & 1023) >> 6) + wn;
  if (sec == 1) {
#pragma unroll
    for (int i = 0; i < 2; i++) {
      f32x4 s1 = {0.f, 0.f, 0.f, 0.f}, s2 = {0.f, 0.f, 0.f, 0.f};
#pragma unroll
      for (int j = 0; j < 4; j++)
#pragma unroll
        for (int r = 0; r < 4; r++) {
          s1[r] += acc[i][j][r];
          s2[r] += acc[i][j][r] * acc[i][j][r];
        }
#pragma unroll
      for (int m = 1; m <= 8; m <<= 1)
#pragma unroll
        for (int r = 0; r < 4; r++) {
          s1[r] += __shfl_xor(s1[r], m);
          s2[r] += __shfl_xor(s2[r], m);
        }
#pragma unroll
      for (int r = 0; r < 4; r++) {
        float mu = s1[r] * (1.f / 64.f);
        float var = s2[r] * (1.f / 64.f) - mu * mu;
        float inv = rsqrtf(var + 1e-5f);
        int row = row0 + wm * 32 + i * 16 + quad * 4 + r;
#pragma unroll
        for (int j = 0; j < 4; j++)
          knb[((size_t)row * NH + hh) * DKH + j * 16 + l16] = __float2bfloat16((acc[i][j][r] - mu) * inv);
      }
    }
  } else if (sec == 2) {
    __syncthreads();
#pragma unroll
    for (int i = 0; i < 2; i++)
#pragma unroll
      for (int j = 0; j < 4; j++)
#pragma unroll
        for (int r = 0; r < 4; r++)
          sm.Vt[w][j * 16 + l16][i * 16 + quad * 4 + r] = bfbits(acc[i][j][r]);
    const int b = row0 >> 10;
    const int t0 = (row0 & 1023) + wm * 32;
    const int bh = b * NH + hh;
    const int cc = lane & 3, ddl = lane >> 2;
#pragma unroll
    for (int pass = 0; pass < 4; pass++) {
      int d = pass * 16 + ddl;
      uint2 a0 = *(const uint2*)&sm.Vt[w][d][cc * 8];
      uint2 a1 = *(const uint2*)&sm.Vt[w][d][cc * 8 + 4];
      uint4 val = {a0.x, a0.y, a1.x, a1.y};
      *(uint4*)(vt + ((size_t)bh * DKH + d) * LQ + t0 + cc * 8) = val;
    }
  }
}

// ---------------- out GEMM: 64x64 tiles, BK=64, fragment-major LDS ----------------
__global__ __launch_bounds__(256) void gemm_out_kernel(
    const __hip_bfloat16* __restrict__ A, const __hip_bfloat16* __restrict__ Bt,
    float* __restrict__ C, int M, int N, int K) {
  __shared__ unsigned short As[8 * 512];
  __shared__ unsigned short Bs[8 * 512];
  const int tid = threadIdx.x;
  const int w = tid >> 6, lane = tid & 63;
  const int quad = lane >> 4, l16 = lane & 15;
  const int wm = w & 1, wn = w >> 1;
  const int row0 = blockIdx.y * 64, col0 = blockIdx.x * 64;
  const int fr = lane & 15;
  const int fk = (lane >> 4) * 8;
  f32x4 acc[2][2];
#pragma unroll
  for (int i = 0; i < 2; i++)
#pragma unroll
    for (int j = 0; j < 2; j++) acc[i][j] = (f32x4){0.f, 0.f, 0.f, 0.f};

  for (int k0 = 0; k0 < K; k0 += 64) {
    __syncthreads();
#pragma unroll
    for (int kk = 0; kk < 2; kk++) {
      const int f = kk * 4 + w;
      const __hip_bfloat16* gA = A + (size_t)(row0 + w * 16 + fr) * K + k0 + kk * 32 + fk;
      __builtin_amdgcn_global_load_lds((gas1_t)gA, (las3_t)((char*)As + f * 1024), 16, 0, 0);
      const __hip_bfloat16* gB = Bt + (size_t)(col0 + w * 16 + fr) * K + k0 + kk * 32 + fk;
      __builtin_amdgcn_global_load_lds((gas1_t)gB, (las3_t)((char*)Bs + f * 1024), 16, 0, 0);
    }
    __syncthreads();
#pragma unroll
    for (int kk = 0; kk < 2; kk++) {
      bf16x8 af[2], bfr[2];
#pragma unroll
      for (int i = 0; i < 2; i++)
        af[i] = *(const bf16x8*)((const char*)As + (((kk * 4 + wm * 2 + i) * 64 + lane) << 4));
#pragma unroll
      for (int j = 0; j < 2; j++)
        bfr[j] = *(const bf16x8*)((const char*)Bs + (((kk * 4 + wn * 2 + j) * 64 + lane) << 4));
#pragma unroll
      for (int i = 0; i < 2; i++)
#pragma unroll
        for (int j = 0; j < 2; j++)
          acc[i][j] = __builtin_amdgcn_mfma_f32_16x16x32_bf16(af[i], bfr[j], acc[i][j], 0, 0, 0);
    }
  }
#pragma unroll
  for (int i = 0; i < 2; i++) {
    int rowb = row0 + wm * 32 + i * 16 + quad * 4;
#pragma unroll
    for (int j = 0; j < 2; j++) {
      int col = col0 + wn * 32 + j * 16 + l16;
#pragma unroll
      for (int r = 0; r < 4; r++)
        C[(size_t)(rowb + r) * N + col] = acc[i][j][r];
    }
  }
}

// ---------------- FUSED attn (blocks 0..511) + scan state pass (blocks 512..1471) ----------------
__global__ __launch_bounds__(256) void attn_state_kernel(
    const __hip_bfloat16* __restrict__ qkvb, const __hip_bfloat16* __restrict__ vt,
    __hip_bfloat16* __restrict__ sob, const __hip_bfloat16* __restrict__ knb,
    const float* __restrict__ ret_g, const float* __restrict__ co_g, float* __restrict__ S) {
  __shared__ __attribute__((aligned(16))) union {
    struct { __hip_bfloat16 Ks[8 * 64 * 8]; __hip_bfloat16 Vs[8 * 64 * 8]; } at;  // 16 KB
    struct { float kb[2][8][64]; float vb[2][8][64]; } st;                        // 8 KB
  } sm;
  const int bx = blockIdx.x;
  const int tid = threadIdx.x;
  if (bx < 512) {
    // ===== attention =====
    const int it = 15 - (bx & 15);
    const int h = (bx >> 4) & 15, b = bx >> 8;
    const int bh = b * NH + h;
    const int w = tid >> 6, lane = tid & 63;
    const int l16 = lane & 15, quad = lane >> 4;
    const int i0 = it * 64;
    const int q_abs = i0 + w * 16 + l16;
    bf16x8 aq[2];
    aq[0] = *(const bf16x8*)(qkvb + (size_t)(b * LQ + q_abs) * 3 * DH + h * DKH + quad * 8);
    aq[1] = *(const bf16x8*)(qkvb + (size_t)(b * LQ + q_abs) * 3 * DH + h * DKH + 32 + quad * 8);
    f32x4 o[4];
#pragma unroll
    for (int dt = 0; dt < 4; dt++) o[dt] = (f32x4){0.f, 0.f, 0.f, 0.f};
    float mrun = -3e38f, lrun = 0.f;

    for (int jt = 0; jt <= it; jt++) {
      const int j0 = jt * 64;
      __syncthreads();
#pragma unroll
      for (int ff = 0; ff < 2; ff++) {
        const int f = w * 2 + ff;
        const int nt = f >> 1, kk = f & 1;
        const __hip_bfloat16* gk = qkvb + (size_t)(b * LQ + j0 + nt * 16 + l16) * 3 * DH + DH +
                                   h * DKH + kk * 32 + quad * 8;
        __builtin_amdgcn_global_load_lds((gas1_t)gk, (las3_t)(sm.at.Ks + f * 512), 16, 0, 0);
        const __hip_bfloat16* gv = vt + ((size_t)bh * DKH + nt * 16 + l16) * LQ + j0 + kk * 32 + quad * 8;
        __builtin_amdgcn_global_load_lds((gas1_t)gv, (las3_t)(sm.at.Vs + f * 512), 16, 0, 0);
      }
      __syncthreads();
      f32x4 s[4];
#pragma unroll
      for (int nt = 0; nt < 4; nt++) s[nt] = (f32x4){0.f, 0.f, 0.f, 0.f};
#pragma unroll
      for (int kk = 0; kk < 2; kk++)
#pragma unroll
        for (int nt = 0; nt < 4; nt++) {
          bf16x8 bk = *(const bf16x8*)(sm.at.Ks + ((nt * 2 + kk) * 64 + lane) * 8);
          s[nt] = __builtin_amdgcn_mfma_f32_16x16x32_bf16(bk, aq[kk], s[nt], 0, 0, 0);
        }
#pragma unroll
      for (int nt = 0; nt < 4; nt++)
#pragma unroll
        for (int r = 0; r < 4; r++) {
          float sv = s[nt][r] * 0.125f;
          if (jt == it && (j0 + nt * 16 + quad * 4 + r > q_abs)) sv = -1e30f;
          s[nt][r] = sv;
        }
      float mx = -3e38f;
#pragma unroll
      for (int nt = 0; nt < 4; nt++)
#pragma unroll
        for (int r = 0; r < 4; r++) mx = fmaxf(mx, s[nt][r]);
      mx = fmaxf(mx, __shfl_xor(mx, 16));
      mx = fmaxf(mx, __shfl_xor(mx, 32));
      float mn = fmaxf(mrun, mx);
      float al = __expf(mrun - mn);
      mrun = mn;
      float p[4][4];
      float rs = 0.f;
#pragma unroll
      for (int nt = 0; nt < 4; nt++)
#pragma unroll
        for (int r = 0; r < 4; r++) {
          float pv = __expf(s[nt][r] - mn);
          p[nt][r] = pv;
          rs += pv;
        }
      rs += __shfl_xor(rs, 16);
      rs += __shfl_xor(rs, 32);
      lrun = lrun * al + rs;
      unsigned pk[4][2];
#pragma unroll
      for (int nt = 0; nt < 4; nt++) {
        pk[nt][0] = pack2bf(p[nt][0], p[nt][1]);
        pk[nt][1] = pack2bf(p[nt][2], p[nt][3]);
      }
      const int srcA = l16 | ((quad & 1) << 5);
      const bool hi_sel = (quad >> 1) != 0;
      bf16x8 ap[2];
#pragma unroll
      for (int kk = 0; kk < 2; kk++) {
        union { unsigned u[4]; bf16x8 v; } cv;
#pragma unroll
        for (int gi = 0; gi < 2; gi++) {
          int src = srcA + (gi << 4);
          unsigned lo0 = (unsigned)__shfl((int)pk[kk * 2][0], src);
          unsigned lo1 = (unsigned)__shfl((int)pk[kk * 2][1], src);
          unsigned hi0 = (unsigned)__shfl((int)pk[kk * 2 + 1][0], src);
          unsigned hi1 = (unsigned)__shfl((int)pk[kk * 2 + 1][1], src);
          cv.u[gi * 2] = hi_sel ? hi0 : lo0;
          cv.u[gi * 2 + 1] = hi_sel ? hi1 : lo1;
        }
        ap[kk] = cv.v;
      }
#pragma unroll
      for (int dt = 0; dt < 4; dt++)
#pragma unroll
        for (int r = 0; r < 4; r++) o[dt][r] *= al;
#pragma unroll
      for (int kk = 0; kk < 2; kk++)
#pragma unroll
        for (int dt = 0; dt < 4; dt++) {
          bf16x8 bv = *(const bf16x8*)(sm.at.Vs + ((dt * 2 + kk) * 64 + lane) * 8);
          o[dt] = __builtin_amdgcn_mfma_f32_16x16x32_bf16(bv, ap[kk], o[dt], 0, 0, 0);
        }
    }
    float inv = 1.f / lrun;
    __hip_bfloat16* ob = sob + ((size_t)(b * LQ + q_abs) * NH + h) * DKH + quad * 4;
#pragma unroll
    for (int dt = 0; dt < 4; dt++) {
      uint2 val = {pack2bf(o[dt][0] * inv, o[dt][1] * inv),
                   pack2bf(o[dt][2] * inv, o[dt][3] * inv)};
      *(uint2*)(ob + dt * 16) = val;
    }
  } else {
    // ===== scan state pass (chunks 0..14) =====
    const int sx = bx - 512;
    const int c = sx >> 6;
    const int xr = sx & 63;
    const int bh = xr >> 1;
    const int half = xr & 1;
    const int bb = bh >> 4, h = bh & 15;
    const int dl = tid >> 3, j = tid & 7;
    const int d = half * 32 + dl;
    float F[8], R[8], Cc[8];
    const int base = h * 4096 + d * 64 + j * 8;
#pragma unroll
    for (int i = 0; i < 8; i++) {
      F[i] = 0.f;
      R[i] = ret_g[base + i];
      Cc[i] = co_g[base + i];
    }
    const int t00 = c * 64;
    const int sten = tid >> 7;
    const int sli = tid & 127;
    const int ss = sli >> 4;
    const int se = (sli & 15) * 4;
    {
      int t = t00 + ss;
      uint2 raw = (sten == 0)
          ? *(const uint2*)(knb + ((size_t)(bb * LQ + t) * NH + h) * DKH + se)
          : *(const uint2*)(qkvb + ((size_t)(bb * LQ + t) * 3 + 2) * DH + h * DKH + se);
      bf4w(sten == 0 ? &sm.st.kb[0][ss][se] : &sm.st.vb[0][ss][se], raw);
    }
    __syncthreads();
    for (int sc = 0; sc < 8; sc++) {
      const int p = sc & 1;
      uint2 raw;
      if (sc < 7) {
        int t = t00 + (sc + 1) * 8 + ss;
        raw = (sten == 0)
            ? *(const uint2*)(knb + ((size_t)(bb * LQ + t) * NH + h) * DKH + se)
            : *(const uint2*)(qkvb + ((size_t)(bb * LQ + t) * 3 + 2) * DH + h * DKH + se);
      }
#pragma unroll
      for (int s = 0; s < 8; s++) {
        float vd = sm.st.vb[p][s][d];
        float4 k0 = *(const float4*)&sm.st.kb[p][s][j * 8];
        float4 k1 = *(const float4*)&sm.st.kb[p][s][j * 8 + 4];
        float ke[8] = {k0.x, k0.y, k0.z, k0.w, k1.x, k1.y, k1.z, k1.w};
#pragma unroll
        for (int i = 0; i < 8; i++) F[i] = fmaf(Cc[i] * vd, ke[i], R[i] * F[i]);
      }
      if (sc < 7) bf4w(sten == 0 ? &sm.st.kb[p ^ 1][ss][se] : &sm.st.vb[p ^ 1][ss][se], raw);
      __syncthreads();
    }
    const size_t sb = ((size_t)c * 2048 + ((size_t)bb * 16 + h) * 64 + d) * 64 + j * 8;
#pragma unroll
    for (int i = 0; i < 8; i++) S[sb + i] = F[i];
  }
}

// ---------------- scan_out: fused combine (batched prefetch) + gate-mix ----------------
__global__ __launch_bounds__(256) void scan_out_kernel(
    const __hip_bfloat16* __restrict__ qkvb, const __hip_bfloat16* __restrict__ knb,
    const float* __restrict__ W_LTM, const float* __restrict__ ret_g, const float* __restrict__ co_g,
    const float* __restrict__ S, const float* __restrict__ ret64,
    const __hip_bfloat16* __restrict__ sob, const float* __restrict__ g,
    __hip_bfloat16* __restrict__ mixb) {
  const int bh = blockIdx.x >> 1;
  const int half = blockIdx.x & 1;
  const int c = 15 - blockIdx.y;            // heavy (high-c) blocks dispatch FIRST
  const int bb = bh >> 4, h = bh & 15;
  const int tid = threadIdx.x;
  const int dl = tid >> 3, j = tid & 7;
  const int d = half * 32 + dl;
  const float gh = g[h];
  float F[8], R[8], Cc[8], W[8];
  const int base = h * 4096 + d * 64 + j * 8;
#pragma unroll
  for (int i = 0; i < 8; i++) {
    F[i] = 0.f;
    R[i] = ret_g[base + i];
    Cc[i] = co_g[base + i];
    W[i] = W_LTM[base + i];
  }
  // combine prologue, batched: issue 8 chunks' loads before consuming (2 serial rounds max)
  if (c > 0) {
    float r64v[8];
#pragma unroll
    for (int i = 0; i < 8; i++) r64v[i] = ret64[base + i];
    const size_t srow = (((size_t)bb * 16 + h) * 64 + d) * 64 + j * 8;
    for (int cb = 0; cb < c; cb += 8) {
      float4 b0[8], b1[8];
#pragma unroll
      for (int t = 0; t < 8; t++) {
        if (cb + t < c) {
          const float* sp = S + (size_t)(cb + t) * 131072 + srow;
          b0[t] = *(const float4*)sp;
          b1[t] = *(const float4*)(sp + 4);
        }
      }
#pragma unroll
      for (int t = 0; t < 8; t++) {
        if (cb + t < c) {
          float sv[8] = {b0[t].x, b0[t].y, b0[t].z, b0[t].w, b1[t].x, b1[t].y, b1[t].z, b1[t].w};
#pragma unroll
          for (int i = 0; i < 8; i++) F[i] = fmaf(r64v[i], F[i], sv[i]);
        }
      }
    }
  }
  __shared__ float qb[2][8][64], kb[2][8][64], vb[2][8][64];
  const int t00 = c * 64;
  const int sten = tid >> 7;
  const int sli = tid & 127;
  const int ss = sli >> 4;
  const int se = (sli & 15) * 4;
  const int vs = tid >> 5;
  const int ve = (tid & 31) * 2;
  {
    int t = t00 + ss, tv = t00 + vs;
    uint2 rqk = (sten == 0)
        ? *(const uint2*)(qkvb + (size_t)(bb * LQ + t) * 3 * DH + h * DKH + se)
        : *(const uint2*)(knb + ((size_t)(bb * LQ + t) * NH + h) * DKH + se);
    unsigned rv = *(const unsigned*)(qkvb + ((size_t)(bb * LQ + tv) * 3 + 2) * DH + h * DKH + ve);
    bf4w(sten == 0 ? &qb[0][ss][se] : &kb[0][ss][se], rqk);
    vb[0][vs][ve] = __uint_as_float(rv << 16);
    vb[0][vs][ve + 1] = __uint_as_float(rv & 0xffff0000u);
  }
  __syncthreads();
  for (int sc = 0; sc < 8; sc++) {
    const int p = sc & 1;
    uint2 rqk;
    unsigned rv;
    if (sc < 7) {
      int t = t00 + (sc + 1) * 8 + ss, tv = t00 + (sc + 1) * 8 + vs;
      rqk = (sten == 0)
          ? *(const uint2*)(qkvb + (size_t)(bb * LQ + t) * 3 * DH + h * DKH + se)
          : *(const uint2*)(knb + ((size_t)(bb * LQ + t) * NH + h) * DKH + se);
      rv = *(const unsigned*)(qkvb + ((size_t)(bb * LQ + tv) * 3 + 2) * DH + h * DKH + ve);
    }
    float ykeep = 0.f;
#pragma unroll
    for (int s = 0; s < 8; s++) {
      float vd = vb[p][s][d];
      float4 k0 = *(const float4*)&kb[p][s][j * 8];
      float4 k1 = *(const float4*)&kb[p][s][j * 8 + 4];
      float4 q0 = *(const float4*)&qb[p][s][j * 8];
      float4 q1 = *(const float4*)&qb[p][s][j * 8 + 4];
      float ke[8] = {k0.x, k0.y, k0.z, k0.w, k1.x, k1.y, k1.z, k1.w};
      float qe[8] = {q0.x, q0.y, q0.z, q0.w, q1.x, q1.y, q1.z, q1.w};
      float yp = 0.f;
#pragma unroll
      for (int i = 0; i < 8; i++) {
        F[i] = fmaf(Cc[i] * vd, ke[i], R[i] * F[i]);
        yp = fmaf(W[i] + F[i], qe[i], yp);
      }
      yp += __shfl_xor(yp, 1);
      yp += __shfl_xor(yp, 2);
      yp += __shfl_xor(yp, 4);
      if (j == s) ykeep = yp;
    }
    {
      const size_t oi = ((size_t)(bb * LQ + t00 + sc * 8 + j) * NH + h) * DKH + d;
      float sv = __bfloat162float(sob[oi]);
      mixb[oi] = __float2bfloat16(gh * sv + (1.f - gh) * ykeep);
    }
    if (sc < 7) {
      bf4w(sten == 0 ? &qb[p ^ 1][ss][se] : &kb[p ^ 1][ss][se], rqk);
      vb[p ^ 1][vs][ve] = __uint_as_float(rv << 16);
      vb[p ^ 1][vs][ve + 1] = __uint_as_float(rv & 0xffff0000u);
    }
    __syncthreads();
  }
}

extern "C" void kernel_launch(void* const* d_in, const int* in_sizes, int n_in,
                              void* d_out, int out_size, void* d_ws, size_t ws_size,
                              hipStream_t stream) {
  (void)in_sizes; (void)n_in; (void)out_size; (void)ws_size;
  const float* x        = (const float*)d_in[0];
  const float* W_qkv    = (const float*)d_in[1];
  const float* W_o      = (const float*)d_in[2];
  const float* W_LTM    = (const float*)d_in[3];
  const float* V_gs     = (const float*)d_in[4];
  const float* V_T0     = (const float*)d_in[5];
  const float* beta_tau = (const float*)d_in[6];
  const float* beta_gm  = (const float*)d_in[7];
  const float* C_ch     = (const float*)d_in[8];
  const float* gamma_   = (const float*)d_in[9];
  const float* alpha_p  = (const float*)d_in[10];
  const float* IC_thr   = (const float*)d_in[11];
  const float* gate     = (const float*)d_in[12];

  float* ws  = (float*)d_ws;
  __hip_bfloat16* qkvb = (__hip_bfloat16*)ws;             // 6291456 bf16
  __hip_bfloat16* knb  = (__hip_bfloat16*)(ws + 3145728); // 2097152 bf16
  __hip_bfloat16* sob  = (__hip_bfloat16*)(ws + 4194304); // 2097152 bf16
  __hip_bfloat16* mixb = (__hip_bfloat16*)(ws + 5242880); // 2097152 bf16
  __hip_bfloat16* vtb  = (__hip_bfloat16*)(ws + 6291456); // 2097152 bf16
  __hip_bfloat16* xb   = (__hip_bfloat16*)(ws + 7340032); // 2097152 bf16
  __hip_bfloat16* wqt  = (__hip_bfloat16*)(ws + 8388608); // 3145728 bf16
  __hip_bfloat16* wot  = (__hip_bfloat16*)(ws + 9961472); // 1048576 bf16
  float* ret   = ws + 10485760;    // 65536
  float* ret64 = ret + 65536;      // 65536
  float* co    = ret64 + 65536;    // 65536
  float* g     = co + 65536;       // 64
  float* Sbuf  = g + 64;           // 15*131072
  float* out = (float*)d_out;

  prep_kernel<<<6400, 256, 0, stream>>>(x, W_qkv, W_o, W_LTM, V_gs, V_T0, beta_tau, beta_gm,
                                        C_ch, gamma_, alpha_p, IC_thr, gate,
                                        xb, wqt, wot, ret, ret64, co, g);
  gemm_qkv_kernel<<<dim3(24, 32), 256, 0, stream>>>(xb, wqt, qkvb, knb, vtb, 2048, 3072, 1024);
  attn_state_kernel<<<1472, 256, 0, stream>>>(qkvb, vtb, sob, knb, ret, co, Sbuf);
  scan_out_kernel<<<dim3(64, 16), 256, 0, stream>>>(qkvb, knb, W_LTM, ret, co, Sbuf, ret64, sob, g, mixb);
  gemm_out_kernel<<<dim3(16, 32), 256, 0, stream>>>(mixb, wot, out, 2048, 1024, 1024);
}